// Round 2
// baseline (412.651 us; speedup 1.0000x reference)
//
#include <hip/hip_runtime.h>
#include <math.h>

#define NPTS 4096
#define DINF 26

__device__ __forceinline__ float ldb(const float* p, int i){ return p[i]; }
__device__ __forceinline__ float lk(float v){ return v >= 0.0f ? v : 0.2f*v; }
__device__ __forceinline__ float wsum64(float v){
#pragma unroll
  for(int o=32;o>0;o>>=1) v += __shfl_down(v,o);
  return v;
}
__device__ __forceinline__ void tangent(float nx,float ny,float nz,float* t1,float* t2){
  float s = (nz >= 0.0f) ? 1.0f : -1.0f;
  float a = -1.0f/(s+nz);
  float b = nx*ny*a;
  t1[0]=1.0f+s*nx*nx*a; t1[1]=s*b; t1[2]=-s*nx;
  t2[0]=b; t2[1]=s+ny*ny*a; t2[2]=-ny;
}

// ---- k0: build f32 working arrays ------------------------------------------
__global__ __launch_bounds__(256) void k0_convert(const float* __restrict__ verts,
                                                  const float* __restrict__ vnorm,
                                                  const float* __restrict__ x,
                                                  float* __restrict__ vertsF,
                                                  float* __restrict__ nF,
                                                  float* __restrict__ pF,
                                                  float* __restrict__ xfF){
  int i = blockIdx.x*blockDim.x + threadIdx.x;
  if(i >= NPTS) return;
#pragma unroll
  for(int d=0;d<3;d++){
    float v = verts[i*3+d];
    vertsF[i*3+d]=v;
    pF[i*3+d]=v*(1.0f/9.0f);
    nF[i*3+d]=vnorm[i*3+d];
  }
#pragma unroll
  for(int c=0;c<16;c++) xfF[i*DINF+c]=x[i*16+c];
}

// ---- k1: curvature pass 1: s0, sx, sxx, un->ns per scale -------------------
// sc layout per scale s (13*NPTS floats): [0,N)=s0, [N,4N)=sx, [4N,10N)=sxx(6 sym), [10N,13N)=ns
__global__ __launch_bounds__(256) void k1_pass1(const float* __restrict__ vertsF,
                                                const float* __restrict__ nF,
                                                float* __restrict__ sc){
  const float inv2s2[5] = {0.5f, 0.125f, 1.0f/18.0f, 0.02f, 0.005f};
  int lane = threadIdx.x & 63;
  int i = blockIdx.x*4 + (threadIdx.x>>6);
  float vix=vertsF[i*3+0], viy=vertsF[i*3+1], viz=vertsF[i*3+2];
  float acc[5][13];
#pragma unroll
  for(int s=0;s<5;s++)
#pragma unroll
    for(int k=0;k<13;k++) acc[s][k]=0.0f;
#pragma unroll 1
  for(int j=lane;j<NPTS;j+=64){
    float vx=vertsF[j*3+0], vy=vertsF[j*3+1], vz=vertsF[j*3+2];
    float nx=nF[j*3+0], ny=nF[j*3+1], nz=nF[j*3+2];
    float dx=vx-vix, dy=vy-viy, dz=vz-viz;
    float d2=dx*dx+dy*dy+dz*dz;
    float x0=vx*vx, x1=vx*vy, x2=vx*vz, x3=vy*vy, x4=vy*vz, x5=vz*vz;
#pragma unroll
    for(int s=0;s<5;s++){
      float w=__expf(-d2*inv2s2[s]);
      acc[s][0]+=w;
      acc[s][1]+=w*vx; acc[s][2]+=w*vy; acc[s][3]+=w*vz;
      acc[s][4]+=w*x0; acc[s][5]+=w*x1; acc[s][6]+=w*x2;
      acc[s][7]+=w*x3; acc[s][8]+=w*x4; acc[s][9]+=w*x5;
      acc[s][10]+=w*nx; acc[s][11]+=w*ny; acc[s][12]+=w*nz;
    }
  }
#pragma unroll
  for(int s=0;s<5;s++)
#pragma unroll
    for(int k=0;k<13;k++) acc[s][k]=wsum64(acc[s][k]);
  if(lane==0){
#pragma unroll
    for(int s=0;s<5;s++){
      float* base = sc + (size_t)s*13*NPTS;
      base[i]=acc[s][0];
      base[NPTS+i*3+0]=acc[s][1]; base[NPTS+i*3+1]=acc[s][2]; base[NPTS+i*3+2]=acc[s][3];
#pragma unroll
      for(int k=0;k<6;k++) base[4*NPTS+i*6+k]=acc[s][4+k];
      float ux=acc[s][10], uy=acc[s][11], uz=acc[s][12];
      float nn=fmaxf(sqrtf(ux*ux+uy*uy+uz*uz), 1e-12f);
      base[10*NPTS+i*3+0]=ux/nn; base[10*NPTS+i*3+1]=uy/nn; base[10*NPTS+i*3+2]=uz/nn;
    }
  }
}

// ---- k2: curvature pass 2: sn, sxn; then solve for features ----------------
__global__ __launch_bounds__(256) void k2_pass2(const float* __restrict__ vertsF,
                                                const float* __restrict__ sc,
                                                float* __restrict__ xfF){
  const float inv2s2[5] = {0.5f, 0.125f, 1.0f/18.0f, 0.02f, 0.005f};
  int lane = threadIdx.x & 63;
  int i = blockIdx.x*4 + (threadIdx.x>>6);
  float vix=vertsF[i*3+0], viy=vertsF[i*3+1], viz=vertsF[i*3+2];
  float acc[5][12];  // sn[3], sxn[9] row-major (verts dim a, ns dim b)
#pragma unroll
  for(int s=0;s<5;s++)
#pragma unroll
    for(int k=0;k<12;k++) acc[s][k]=0.0f;
#pragma unroll 1
  for(int j=lane;j<NPTS;j+=64){
    float vx=vertsF[j*3+0], vy=vertsF[j*3+1], vz=vertsF[j*3+2];
    float dx=vx-vix, dy=vy-viy, dz=vz-viz;
    float d2=dx*dx+dy*dy+dz*dz;
#pragma unroll
    for(int s=0;s<5;s++){
      const float* nsb = sc + (size_t)s*13*NPTS + 10*NPTS;
      float nsx=nsb[j*3+0], nsy=nsb[j*3+1], nsz=nsb[j*3+2];
      float w=__expf(-d2*inv2s2[s]);
      acc[s][0]+=w*nsx; acc[s][1]+=w*nsy; acc[s][2]+=w*nsz;
      float wx=w*vx, wy=w*vy, wz=w*vz;
      acc[s][3]+=wx*nsx; acc[s][4]+=wx*nsy; acc[s][5]+=wx*nsz;
      acc[s][6]+=wy*nsx; acc[s][7]+=wy*nsy; acc[s][8]+=wy*nsz;
      acc[s][9]+=wz*nsx; acc[s][10]+=wz*nsy; acc[s][11]+=wz*nsz;
    }
  }
#pragma unroll
  for(int s=0;s<5;s++)
#pragma unroll
    for(int k=0;k<12;k++) acc[s][k]=wsum64(acc[s][k]);
  if(lane==0){
    float v[3]={vix,viy,viz};
#pragma unroll
    for(int s=0;s<5;s++){
      const float* base = sc + (size_t)s*13*NPTS;
      float s0=base[i];
      float sx[3]={base[NPTS+i*3+0], base[NPTS+i*3+1], base[NPTS+i*3+2]};
      float sxx6[6];
#pragma unroll
      for(int k=0;k<6;k++) sxx6[k]=base[4*NPTS+i*6+k];
      float nsi[3]={base[10*NPTS+i*3+0], base[10*NPTS+i*3+1], base[10*NPTS+i*3+2]};
      float sn[3]={acc[s][0],acc[s][1],acc[s][2]};
      float sxn[3][3];
#pragma unroll
      for(int a=0;a<3;a++)
#pragma unroll
        for(int b=0;b<3;b++) sxn[a][b]=acc[s][3+a*3+b];
      const int m6[3][3]={{0,1,2},{1,3,4},{2,4,5}};
      float cxx[3][3], cxn[3][3];
#pragma unroll
      for(int a=0;a<3;a++)
#pragma unroll
        for(int b=0;b<3;b++){
          cxx[a][b]=sxx6[m6[a][b]] - v[a]*sx[b] - sx[a]*v[b] + s0*v[a]*v[b];
          cxn[a][b]=sxn[a][b]    - v[a]*sn[b] - sx[a]*nsi[b] + s0*v[a]*nsi[b];
        }
      float t1[3],t2[3];
      tangent(nsi[0],nsi[1],nsi[2],t1,t2);
      float ppt[2][2], pqt[2][2];
#pragma unroll
      for(int k=0;k<2;k++){
        const float* tk = (k==0)?t1:t2;
#pragma unroll
        for(int l=0;l<2;l++){
          const float* tl = (l==0)?t1:t2;
          float accx=0.0f, accn=0.0f;
#pragma unroll
          for(int a=0;a<3;a++)
#pragma unroll
            for(int b=0;b<3;b++){
              accx += tk[a]*cxx[a][b]*tl[b];
              accn += tk[a]*cxn[a][b]*tl[b];
            }
          ppt[k][l]=accx + ((k==l)?0.01f:0.0f);
          pqt[k][l]=accn;
        }
      }
      float det = ppt[0][0]*ppt[1][1]-ppt[0][1]*ppt[1][0];
      float id = 1.0f/det;
      float S00=( ppt[1][1]*pqt[0][0]-ppt[0][1]*pqt[1][0])*id;
      float S01=( ppt[1][1]*pqt[0][1]-ppt[0][1]*pqt[1][1])*id;
      float S10=(-ppt[1][0]*pqt[0][0]+ppt[0][0]*pqt[1][0])*id;
      float S11=(-ppt[1][0]*pqt[0][1]+ppt[0][0]*pqt[1][1])*id;
      float f0=fminf(fmaxf(S00+S11,-1.0f),1.0f);
      float f1=fminf(fmaxf(S00*S11-S01*S10,-1.0f),1.0f);
      xfF[i*DINF+16+2*s]=f0;
      xfF[i*DINF+17+2*s]=f1;
    }
  }
}

// ---- k3: per-point small MLPs (os -> w scalar; ni -> hPre) + GN-in stats ---
__global__ __launch_bounds__(256) void k3_mlps(const float* __restrict__ xfF,
    const float* os_w1, const float* os_b1, const float* os_w2, const float* os_b2,
    const float* ni_w1, const float* ni_b1, const float* ni_w2, const float* ni_b2,
    float* __restrict__ wOS, float* __restrict__ hPre, float* __restrict__ stats){
  int i = blockIdx.x*256 + threadIdx.x;
  int lane = threadIdx.x & 63;
  float xf[DINF];
#pragma unroll
  for(int k=0;k<DINF;k++) xf[k]=xfF[i*DINF+k];
  float h1[16];
#pragma unroll
  for(int o=0;o<16;o++){
    float t=ldb(os_b1,o);
#pragma unroll
    for(int k=0;k<DINF;k++) t += xf[k]*ldb(os_w1,o*DINF+k);
    h1[o]=lk(t);
  }
  float w=ldb(os_b2,0);
#pragma unroll
  for(int o=0;o<16;o++) w += h1[o]*ldb(os_w2,o);
  wOS[i]=w;
#pragma unroll
  for(int o=0;o<16;o++){
    float t=ldb(ni_b1,o);
#pragma unroll
    for(int k=0;k<DINF;k++) t += xf[k]*ldb(ni_w1,o*DINF+k);
    h1[o]=lk(t);
  }
  float h2[16];
#pragma unroll
  for(int o=0;o<16;o++){
    float t=ldb(ni_b2,o);
#pragma unroll
    for(int k=0;k<16;k++) t += h1[k]*ldb(ni_w2,o*16+k);
    h2[o]=lk(t);
    hPre[i*16+o]=h2[o];
  }
  float gs[4]={0,0,0,0}, gq[4]={0,0,0,0};
#pragma unroll
  for(int c=0;c<16;c++){ gs[c>>2]+=h2[c]; gq[c>>2]+=h2[c]*h2[c]; }
  __shared__ float ls[8];
  if(threadIdx.x<8) ls[threadIdx.x]=0.0f;
  __syncthreads();
#pragma unroll
  for(int g=0;g<4;g++){ gs[g]=wsum64(gs[g]); gq[g]=wsum64(gq[g]); }
  if(lane==0){
#pragma unroll
    for(int g=0;g<4;g++){ atomicAdd(&ls[2*g],gs[g]); atomicAdd(&ls[2*g+1],gq[g]); }
  }
  __syncthreads();
  if(threadIdx.x<8) atomicAdd(&stats[threadIdx.x], ls[threadIdx.x]);
}

// ---- k3c: apply GroupNorm -> hF --------------------------------------------
__global__ __launch_bounds__(256) void k3c_gn(const float* __restrict__ hPre,
                                              const float* __restrict__ stats,
                                              const float* gw, const float* gb,
                                              float* __restrict__ hF){
  int i = blockIdx.x*256 + threadIdx.x;
  float m[4], r[4];
#pragma unroll
  for(int g=0;g<4;g++){
    float mean = stats[2*g]*(1.0f/(4.0f*NPTS));
    float var  = stats[2*g+1]*(1.0f/(4.0f*NPTS)) - mean*mean;
    m[g]=mean; r[g]=1.0f/sqrtf(var+1e-5f);
  }
#pragma unroll
  for(int c=0;c<16;c++){
    int g=c>>2;
    hF[i*16+c]=(hPre[i*16+c]-m[g])*r[g]*ldb(gw,c)+ldb(gb,c);
  }
}

// ---- k4: ov accumulation -> nuv --------------------------------------------
__global__ __launch_bounds__(256) void k4_ov(const float* __restrict__ pF,
                                             const float* __restrict__ nF,
                                             const float* __restrict__ wOS,
                                             float* __restrict__ nuvF){
  int lane = threadIdx.x & 63;
  int i = blockIdx.x*4 + (threadIdx.x>>6);
  float pix=pF[i*3+0], piy=pF[i*3+1], piz=pF[i*3+2];
  float nix=nF[i*3+0], niy=nF[i*3+1], niz=nF[i*3+2];
  float a0=0,a1=0,a2=0,a3=0;
#pragma unroll 1
  for(int j=lane;j<NPTS;j+=64){
    float px=pF[j*3+0], py=pF[j*3+1], pz=pF[j*3+2];
    float nx=nF[j*3+0], ny=nF[j*3+1], nz=nF[j*3+2];
    float wj=wOS[j];
    float dx=px-pix, dy=py-piy, dz=pz-piz;
    float d2=dx*dx+dy*dy+dz*dz;
    float f=2.0f-(nx*nix+ny*niy+nz*niz);
    float Wv=__expf(-d2*f*f);
    float Ww=Wv*wj;
    a0+=Ww*px; a1+=Ww*py; a2+=Ww*pz; a3+=Ww;
  }
  a0=wsum64(a0); a1=wsum64(a1); a2=wsum64(a2); a3=wsum64(a3);
  if(lane==0){
    float o0=a0-a3*pix, o1=a1-a3*piy, o2=a2-a3*piz;
    float t1[3],t2[3];
    tangent(nix,niy,niz,t1,t2);
    float ov0=t1[0]*o0+t1[1]*o1+t1[2]*o2+1e-5f;
    float ov1=t2[0]*o0+t2[1]*o1+t2[2]*o2+1e-5f;
    float inv=1.0f/sqrtf(ov0*ov0+ov1*ov1);
    float ex=ov0*inv, ey=ov1*inv;
    nuvF[i*9+0]=nix; nuvF[i*9+1]=niy; nuvF[i*9+2]=niz;
    nuvF[i*9+3]= ex*t1[0]+ey*t2[0]; nuvF[i*9+4]= ex*t1[1]+ey*t2[1]; nuvF[i*9+5]= ex*t1[2]+ey*t2[2];
    nuvF[i*9+6]=-ey*t1[0]+ex*t2[0]; nuvF[i*9+7]=-ey*t1[1]+ex*t2[1]; nuvF[i*9+8]=-ey*t1[2]+ex*t2[2];
  }
}

// ---- k5: the big conv block -> xi ------------------------------------------
__global__ __launch_bounds__(256,2) void k5_conv(const float* __restrict__ pF,
                                                 const float* __restrict__ nF,
                                                 const float* __restrict__ nuvF,
                                                 const float* __restrict__ hF,
                                                 const float* cv_a1, const float* cv_b1,
                                                 const float* cv_a2, const float* cv_b2,
                                                 float* __restrict__ xiF){
  int lane = threadIdx.x & 63;
  int i = blockIdx.x*4 + (threadIdx.x>>6);
  float pix=pF[i*3+0], piy=pF[i*3+1], piz=pF[i*3+2];
  float nu[9];
#pragma unroll
  for(int k=0;k<9;k++) nu[k]=nuvF[i*9+k];
  float a1w[8][3], b1w[8];
#pragma unroll
  for(int c=0;c<8;c++){
    a1w[c][0]=ldb(cv_a1,c*3+0); a1w[c][1]=ldb(cv_a1,c*3+1); a1w[c][2]=ldb(cv_a1,c*3+2);
    b1w[c]=ldb(cv_b1,c);
  }
  float G[16][8], gg[16];
#pragma unroll
  for(int h=0;h<16;h++){
    gg[h]=0.0f;
#pragma unroll
    for(int c=0;c<8;c++) G[h][c]=0.0f;
  }
#pragma unroll 1
  for(int j=lane;j<NPTS;j+=64){
    float px=pF[j*3+0], py=pF[j*3+1], pz=pF[j*3+2];
    float nx=nF[j*3+0], ny=nF[j*3+1], nz=nF[j*3+2];
    float dx=px-pix, dy=py-piy, dz=pz-piz;
    float d2=dx*dx+dy*dy+dz*dz;
    float f=2.0f-(nx*nu[0]+ny*nu[1]+nz*nu[2]);
    float win=__expf(-d2*f*f);
    float X0=nu[0]*dx+nu[1]*dy+nu[2]*dz;
    float X1=nu[3]*dx+nu[4]*dy+nu[5]*dz;
    float X2=nu[6]*dx+nu[7]*dy+nu[8]*dz;
    float wr[8];
#pragma unroll
    for(int c=0;c<8;c++){
      float r=X0*a1w[c][0]+X1*a1w[c][1]+X2*a1w[c][2]+b1w[c];
      wr[c]=win*fmaxf(r,0.0f);
    }
    const float4* h4=(const float4*)(hF+j*16);
    float4 hA=h4[0], hB=h4[1], hC=h4[2], hD=h4[3];
    float hv[16]={hA.x,hA.y,hA.z,hA.w, hB.x,hB.y,hB.z,hB.w,
                  hC.x,hC.y,hC.z,hC.w, hD.x,hD.y,hD.z,hD.w};
#pragma unroll
    for(int h=0;h<16;h++){
      gg[h]+=win*hv[h];
#pragma unroll
      for(int c=0;c<8;c++) G[h][c]+=hv[h]*wr[c];
    }
  }
#pragma unroll
  for(int h=0;h<16;h++){
    float xi=gg[h]*ldb(cv_b2,h);
#pragma unroll
    for(int c=0;c<8;c++) xi += G[h][c]*ldb(cv_a2,h*8+c);
    xi=wsum64(xi);
    if(lane==0) xiF[i*16+h]=xi;
  }
}

// ---- k6a: no-MLP -> tF + GN-out stats --------------------------------------
__global__ __launch_bounds__(256) void k6a(const float* __restrict__ xiF,
    const float* no_w1, const float* no_b1, const float* no_w2, const float* no_b2,
    float* __restrict__ tF, float* __restrict__ stats2){
  int i = blockIdx.x*256 + threadIdx.x;
  int lane = threadIdx.x & 63;
  float xi[16];
#pragma unroll
  for(int k=0;k<16;k++) xi[k]=xiF[i*16+k];
  float t1[16];
#pragma unroll
  for(int o=0;o<16;o++){
    float t=ldb(no_b1,o);
#pragma unroll
    for(int k=0;k<16;k++) t += xi[k]*ldb(no_w1,o*16+k);
    t1[o]=lk(t);
  }
  float t2[16];
#pragma unroll
  for(int o=0;o<16;o++){
    float t=ldb(no_b2,o);
#pragma unroll
    for(int k=0;k<16;k++) t += t1[k]*ldb(no_w2,o*16+k);
    t2[o]=lk(t);
    tF[i*16+o]=t2[o];
  }
  float gs[4]={0,0,0,0}, gq[4]={0,0,0,0};
#pragma unroll
  for(int c=0;c<16;c++){ gs[c>>2]+=t2[c]; gq[c>>2]+=t2[c]*t2[c]; }
  __shared__ float ls[8];
  if(threadIdx.x<8) ls[threadIdx.x]=0.0f;
  __syncthreads();
#pragma unroll
  for(int g=0;g<4;g++){ gs[g]=wsum64(gs[g]); gq[g]=wsum64(gq[g]); }
  if(lane==0){
#pragma unroll
    for(int g=0;g<4;g++){ atomicAdd(&ls[2*g],gs[g]); atomicAdd(&ls[2*g+1],gq[g]); }
  }
  __syncthreads();
  if(threadIdx.x<8) atomicAdd(&stats2[threadIdx.x], ls[threadIdx.x]);
}

// ---- k6c: GN-out + ll MLP + lt skip -> out (f32) ---------------------------
__global__ __launch_bounds__(256) void k6c(const float* __restrict__ tF,
    const float* __restrict__ xfF, const float* __restrict__ stats2,
    const float* gw, const float* gb,
    const float* ll_w1, const float* ll_b1, const float* ll_w2, const float* ll_b2,
    const float* lt_w, const float* lt_b,
    float* __restrict__ out){
  int i = blockIdx.x*256 + threadIdx.x;
  float m[4], r[4];
#pragma unroll
  for(int g=0;g<4;g++){
    float mean = stats2[2*g]*(1.0f/(4.0f*NPTS));
    float var  = stats2[2*g+1]*(1.0f/(4.0f*NPTS)) - mean*mean;
    m[g]=mean; r[g]=1.0f/sqrtf(var+1e-5f);
  }
  float tn[16];
#pragma unroll
  for(int c=0;c<16;c++){
    int g=c>>2;
    tn[c]=(tF[i*16+c]-m[g])*r[g]*ldb(gw,c)+ldb(gb,c);
  }
  float z1[16];
#pragma unroll
  for(int o=0;o<16;o++){
    float t=ldb(ll_b1,o);
#pragma unroll
    for(int k=0;k<16;k++) t += tn[k]*ldb(ll_w1,o*16+k);
    z1[o]=fmaxf(t,0.0f);
  }
  float xf[DINF];
#pragma unroll
  for(int k=0;k<DINF;k++) xf[k]=xfF[i*DINF+k];
#pragma unroll
  for(int o=0;o<16;o++){
    float z=ldb(ll_b2,o);
#pragma unroll
    for(int k=0;k<16;k++) z += z1[k]*ldb(ll_w2,o*16+k);
    float lt=ldb(lt_b,o);
#pragma unroll
    for(int k=0;k<DINF;k++) lt += xf[k]*ldb(lt_w,o*DINF+k);
    out[i*16+o]=z+lt;
  }
}

extern "C" void kernel_launch(void* const* d_in, const int* in_sizes, int n_in,
                              void* d_out, int out_size, void* d_ws, size_t ws_size,
                              hipStream_t stream){
  const float* verts    = (const float*)d_in[0];
  const float* vnormals = (const float*)d_in[1];
  const float* x        = (const float*)d_in[2];
  const float* os_w1    = (const float*)d_in[3];
  const float* os_b1    = (const float*)d_in[4];
  const float* os_w2    = (const float*)d_in[5];
  const float* os_b2    = (const float*)d_in[6];
  const float* ni_w1    = (const float*)d_in[7];
  const float* ni_b1    = (const float*)d_in[8];
  const float* ni_w2    = (const float*)d_in[9];
  const float* ni_b2    = (const float*)d_in[10];
  const float* gn_in_w  = (const float*)d_in[11];
  const float* gn_in_b  = (const float*)d_in[12];
  const float* cv_a1    = (const float*)d_in[13];
  const float* cv_b1    = (const float*)d_in[14];
  const float* cv_a2    = (const float*)d_in[15];
  const float* cv_b2    = (const float*)d_in[16];
  const float* no_w1    = (const float*)d_in[17];
  const float* no_b1    = (const float*)d_in[18];
  const float* no_w2    = (const float*)d_in[19];
  const float* no_b2    = (const float*)d_in[20];
  const float* gn_out_w = (const float*)d_in[21];
  const float* gn_out_b = (const float*)d_in[22];
  const float* ll_w1    = (const float*)d_in[23];
  const float* ll_b1    = (const float*)d_in[24];
  const float* ll_w2    = (const float*)d_in[25];
  const float* ll_b2    = (const float*)d_in[26];
  const float* lt_w     = (const float*)d_in[27];
  const float* lt_b     = (const float*)d_in[28];

  float* W = (float*)d_ws;
  size_t off = 0;
  float* vertsF = W + off; off += (size_t)3*NPTS;
  float* nF     = W + off; off += (size_t)3*NPTS;
  float* pF     = W + off; off += (size_t)3*NPTS;
  float* xfF    = W + off; off += (size_t)DINF*NPTS;
  float* sc     = W + off; off += (size_t)13*NPTS*5;
  float* wOS    = W + off; off += (size_t)NPTS;
  float* hPre   = W + off; off += (size_t)16*NPTS;
  float* hF     = W + off; off += (size_t)16*NPTS;
  float* nuvF   = W + off; off += (size_t)9*NPTS;
  float* xiF    = W + off; off += (size_t)16*NPTS;
  float* tF     = W + off; off += (size_t)16*NPTS;
  float* stats  = W + off; off += 16;

  hipMemsetAsync(stats, 0, 16*sizeof(float), stream);

  k0_convert<<<NPTS/256, 256, 0, stream>>>(verts, vnormals, x, vertsF, nF, pF, xfF);
  k1_pass1<<<NPTS/4, 256, 0, stream>>>(vertsF, nF, sc);
  k2_pass2<<<NPTS/4, 256, 0, stream>>>(vertsF, sc, xfF);
  k3_mlps<<<NPTS/256, 256, 0, stream>>>(xfF, os_w1, os_b1, os_w2, os_b2,
                                        ni_w1, ni_b1, ni_w2, ni_b2, wOS, hPre, stats);
  k3c_gn<<<NPTS/256, 256, 0, stream>>>(hPre, stats, gn_in_w, gn_in_b, hF);
  k4_ov<<<NPTS/4, 256, 0, stream>>>(pF, nF, wOS, nuvF);
  k5_conv<<<NPTS/4, 256, 0, stream>>>(pF, nF, nuvF, hF, cv_a1, cv_b1, cv_a2, cv_b2, xiF);
  k6a<<<NPTS/256, 256, 0, stream>>>(xiF, no_w1, no_b1, no_w2, no_b2, tF, stats+8);
  k6c<<<NPTS/256, 256, 0, stream>>>(tF, xfF, stats+8, gn_out_w, gn_out_b,
                                    ll_w1, ll_b1, ll_w2, ll_b2, lt_w, lt_b, (float*)d_out);
}